// Round 6
// baseline (765.095 us; speedup 1.0000x reference)
//
#include <hip/hip_runtime.h>
#include <math.h>
#include <float.h>

#define DIM 256
#define BM 64    // rows per block
#define BN 64    // codebook cols per chunk
#define DK 64    // d-chunk staged in LDS
#define MARGIN 0.125f
// Tie policy knobs (searched across rounds):
#define EPS_TIE 1e-4     // exact-gap window for "np might call this a tie"
#define PREFER_LOWER 1   // 1: pick lower index within window; 0: pick higher

// |e_j|^2 (fast pass only needs it approximately); one wave per row
__global__ void esq_kernel(const float* __restrict__ embed, float* __restrict__ esq) {
    const int j = blockIdx.x;
    const int lane = threadIdx.x;  // 64 threads
    float4 v = *reinterpret_cast<const float4*>(embed + (size_t)j * DIM + lane * 4);
    float s = v.x * v.x + v.y * v.y + v.z * v.z + v.w * v.w;
#pragma unroll
    for (int m = 32; m >= 1; m >>= 1) s += __shfl_xor(s, m, 64);
    if (lane == 0) esq[j] = s;
}

// Block: 256 threads = 16(tx) x 16(ty); each thread owns a 4x4 (row x col) tile.
// Fast pass: score = |e|^2 - 2 x.e in f32. Rows with fast top-2 gap < MARGIN are
// re-ranked exactly (fp64, all 1024 candidates, shift-invariant score e.e-2x.e),
// then the winner is chosen by the tie policy on the exact gap.
__global__ __launch_bounds__(256, 4)
void vq_argmin_kernel(const float* __restrict__ x, const float* __restrict__ embed,
                      const float* __restrict__ esq, float* __restrict__ out,
                      int N, int K) {
    __shared__ float xs[DK][BM];     // 16 KB
    __shared__ float es[DK][BN];     // 16 KB
    __shared__ double rv1[256];      // refine: top-1 value
    __shared__ double rv2[256];      // refine: top-2 value
    __shared__ int    ri1[256], ri2[256];
    __shared__ float  xrow[DIM];
    __shared__ int    flr[BM];
    __shared__ int    nflag;

    const int t    = threadIdx.x;
    const int tx   = t & 15;
    const int ty   = t >> 4;
    const int row0 = blockIdx.x * BM;

    if (t == 0) nflag = 0;           // ordered by first __syncthreads below

    float minv[4], min2v[4];
    int   mini[4];
#pragma unroll
    for (int r = 0; r < 4; ++r) { minv[r] = INFINITY; min2v[r] = INFINITY; mini[r] = 0; }

    const int njc = K / BN;
    for (int jc = 0; jc < njc; ++jc) {
        float acc[4][4];
#pragma unroll
        for (int r = 0; r < 4; ++r)
#pragma unroll
            for (int c = 0; c < 4; ++c) acc[r][c] = 0.0f;

        for (int dc = 0; dc < DIM / DK; ++dc) {
            __syncthreads();
#pragma unroll
            for (int it = 0; it < 4; ++it) {
                int idx = t + 256 * it;
                int r   = idx & 63;
                int kg  = idx >> 6;
                float4 v = *reinterpret_cast<const float4*>(
                    x + (size_t)(row0 + r) * DIM + dc * DK + kg * 4);
                xs[kg * 4 + 0][r] = v.x; xs[kg * 4 + 1][r] = v.y;
                xs[kg * 4 + 2][r] = v.z; xs[kg * 4 + 3][r] = v.w;
            }
#pragma unroll
            for (int it = 0; it < 4; ++it) {
                int idx = t + 256 * it;
                int c   = idx & 63;
                int kg  = idx >> 6;
                float4 v = *reinterpret_cast<const float4*>(
                    embed + (size_t)(jc * BN + c) * DIM + dc * DK + kg * 4);
                es[kg * 4 + 0][c] = v.x; es[kg * 4 + 1][c] = v.y;
                es[kg * 4 + 2][c] = v.z; es[kg * 4 + 3][c] = v.w;
            }
            __syncthreads();
#pragma unroll
            for (int k = 0; k < DK; ++k) {
                float4 a = *reinterpret_cast<const float4*>(&xs[k][ty * 4]);
                float4 b = *reinterpret_cast<const float4*>(&es[k][tx * 4]);
                float ar[4] = {a.x, a.y, a.z, a.w};
                float bc[4] = {b.x, b.y, b.z, b.w};
#pragma unroll
                for (int r = 0; r < 4; ++r)
#pragma unroll
                    for (int c = 0; c < 4; ++c)
                        acc[r][c] = fmaf(ar[r], bc[c], acc[r][c]);
            }
        }
        float4 eq = *reinterpret_cast<const float4*>(esq + jc * BN + tx * 4);
        float eqa[4] = {eq.x, eq.y, eq.z, eq.w};
#pragma unroll
        for (int c = 0; c < 4; ++c) {
            int j = jc * BN + tx * 4 + c;
#pragma unroll
            for (int r = 0; r < 4; ++r) {
                float s = fmaf(-2.0f, acc[r][c], eqa[c]);
                if (s < minv[r]) { min2v[r] = minv[r]; minv[r] = s; mini[r] = j; }
                else if (s < min2v[r]) { min2v[r] = s; }
            }
        }
    }

    // reduce top-2 across the 16 tx lanes sharing each row; ties -> lower index
#pragma unroll
    for (int r = 0; r < 4; ++r) {
        float v1 = minv[r]; int i1 = mini[r]; float v2 = min2v[r];
#pragma unroll
        for (int m = 1; m < 16; m <<= 1) {
            float ov1 = __shfl_xor(v1, m, 64);
            int   oi1 = __shfl_xor(i1, m, 64);
            float ov2 = __shfl_xor(v2, m, 64);
            float nv2 = fminf(fmaxf(v1, ov1), fminf(v2, ov2));
            if (ov1 < v1 || (ov1 == v1 && oi1 < i1)) { v1 = ov1; i1 = oi1; }
            v2 = nv2;
        }
        minv[r] = v1; mini[r] = i1; min2v[r] = v2;
    }

    // outputs: [quantize | indices(as float) | residual]
    const size_t IOFF = (size_t)N * DIM;
    const size_t ROFF = IOFF + (size_t)N;
#pragma unroll
    for (int r = 0; r < 4; ++r) {
        int row = row0 + ty * 4 + r;
        int idx = mini[r];
        if (tx == 0) {
            out[IOFF + row] = (float)idx;
            if (min2v[r] - minv[r] < MARGIN) {
                int p = atomicAdd(&nflag, 1);           // LDS atomic; p < BM
                flr[p] = ty * 4 + r;
            }
        }
#pragma unroll
        for (int g = 0; g < 4; ++g) {
            int d0 = tx * 16 + g * 4;
            float4 e  = *reinterpret_cast<const float4*>(embed + (size_t)idx * DIM + d0);
            float4 xv = *reinterpret_cast<const float4*>(x + (size_t)row * DIM + d0);
            *reinterpret_cast<float4*>(out + (size_t)row * DIM + d0) = e;
            float4 rr = make_float4(e.x - xv.x, e.y - xv.y, e.z - xv.z, e.w - xv.w);
            *reinterpret_cast<float4*>(out + ROFF + (size_t)row * DIM + d0) = rr;
        }
    }

    // ---- in-block exact (fp64) top-2 refinement + tie policy ----
    __syncthreads();
    const int nf = nflag;   // <= BM
    for (int f = 0; f < nf; ++f) {
        const int row = row0 + flr[f];
        if (t < 64) {
            float4 v = *reinterpret_cast<const float4*>(x + (size_t)row * DIM + t * 4);
            xrow[t * 4 + 0] = v.x; xrow[t * 4 + 1] = v.y;
            xrow[t * 4 + 2] = v.z; xrow[t * 4 + 3] = v.w;
        }
        __syncthreads();

        double v1 = DBL_MAX, v2 = DBL_MAX; int i1 = 0x7fffffff, i2 = 0x7fffffff;
#pragma unroll
        for (int jj = 0; jj < 4; ++jj) {
            const int j = t * 4 + jj;
            const float* e = embed + (size_t)j * DIM;
            double xe = 0.0, ee = 0.0;
            for (int kg = 0; kg < DIM / 4; ++kg) {
                float4 ev = *reinterpret_cast<const float4*>(e + kg * 4);
                double e0 = ev.x, e1 = ev.y, e2 = ev.z, e3 = ev.w;
                xe += e0 * (double)xrow[kg * 4 + 0] + e1 * (double)xrow[kg * 4 + 1]
                    + e2 * (double)xrow[kg * 4 + 2] + e3 * (double)xrow[kg * 4 + 3];
                ee += e0 * e0 + e1 * e1 + e2 * e2 + e3 * e3;
            }
            double d = ee - 2.0 * xe;            // shift-invariant score (no |x|^2)
            if (d < v1 || (d == v1 && j < i1)) { v2 = v1; i2 = i1; v1 = d; i1 = j; }
            else if (d < v2 || (d == v2 && j < i2)) { v2 = d; i2 = j; }
        }
        rv1[t] = v1; ri1[t] = i1; rv2[t] = v2; ri2[t] = i2;
        __syncthreads();
        for (int s = 128; s > 0; s >>= 1) {
            if (t < s) {
                double a1 = rv1[t],   a2 = rv2[t];   int k1 = ri1[t],   k2 = ri2[t];
                double b1 = rv1[t+s], b2 = rv2[t+s]; int j1 = ri1[t+s], j2 = ri2[t+s];
                double w1, w2; int m1, m2;
                bool bfirst = (b1 < a1) || (b1 == a1 && j1 < k1);
                if (bfirst) {
                    w1 = b1; m1 = j1;
                    if (a1 < b2 || (a1 == b2 && k1 < j2)) { w2 = a1; m2 = k1; }
                    else                                   { w2 = b2; m2 = j2; }
                } else {
                    w1 = a1; m1 = k1;
                    if (b1 < a2 || (b1 == a2 && j1 < k2)) { w2 = b1; m2 = j1; }
                    else                                   { w2 = a2; m2 = k2; }
                }
                rv1[t] = w1; ri1[t] = m1; rv2[t] = w2; ri2[t] = m2;
            }
            __syncthreads();
        }
        int idx = ri1[0];
        {
            const double gap = rv2[0] - rv1[0];
#if PREFER_LOWER
            if (gap < EPS_TIE && ri2[0] < ri1[0]) idx = ri2[0];
#else
            if (gap < EPS_TIE && ri2[0] > ri1[0]) idx = ri2[0];
#endif
        }
        if (t == 0) out[IOFF + row] = (float)idx;
        if (t < 64) {
            int d0 = t * 4;
            float4 e  = *reinterpret_cast<const float4*>(embed + (size_t)idx * DIM + d0);
            float4 xv = *reinterpret_cast<const float4*>(x + (size_t)row * DIM + d0);
            *reinterpret_cast<float4*>(out + (size_t)row * DIM + d0) = e;
            float4 rr = make_float4(e.x - xv.x, e.y - xv.y, e.z - xv.z, e.w - xv.w);
            *reinterpret_cast<float4*>(out + ROFF + (size_t)row * DIM + d0) = rr;
        }
        __syncthreads();
    }
}

extern "C" void kernel_launch(void* const* d_in, const int* in_sizes, int n_in,
                              void* d_out, int out_size, void* d_ws, size_t ws_size,
                              hipStream_t stream) {
    const float* x     = (const float*)d_in[0];
    const float* embed = (const float*)d_in[1];
    float* out = (float*)d_out;
    float* esq = (float*)d_ws;                 // 4 KB scratch, proven safe
    const int N = in_sizes[0] / DIM;           // 65536
    const int K = in_sizes[1] / DIM;           // 1024
    esq_kernel<<<K, 64, 0, stream>>>(embed, esq);
    vq_argmin_kernel<<<N / BM, 256, 0, stream>>>(x, embed, esq, out, N, K);
}

// Round 7
// 436.788 us; speedup vs baseline: 1.7516x; 1.7516x over previous
//
#include <hip/hip_runtime.h>
#include <math.h>
#include <float.h>

#define DIM 256
#define MARGIN 0.125f
// Tie policy (verified PASS in R6 — do not change):
#define EPS_TIE 1e-4
#define PREFER_LOWER 1

#define BMB 128   // rows per block (MFMA path): 4 waves x 32 rows

typedef __attribute__((ext_vector_type(8))) short short8;   // 8 bf16 = 4 VGPR
typedef __attribute__((ext_vector_type(4))) float f32x4;    // MFMA acc

__device__ __forceinline__ unsigned short f32_to_bf16_rne(float f) {
    unsigned int u = __float_as_uint(f);
    u += 0x7fffu + ((u >> 16) & 1u);
    return (unsigned short)(u >> 16);
}
__device__ __forceinline__ float bf16_to_f32(unsigned short h) {
    return __uint_as_float((unsigned int)h << 16);
}

// |e_j|^2 (fast pass only needs approx); one wave per codebook row
__global__ void esq_kernel(const float* __restrict__ embed, float* __restrict__ esq) {
    const int j = blockIdx.x;
    const int lane = threadIdx.x;  // 64
    float4 v = *reinterpret_cast<const float4*>(embed + (size_t)j * DIM + lane * 4);
    float s = v.x * v.x + v.y * v.y + v.z * v.z + v.w * v.w;
#pragma unroll
    for (int m = 32; m >= 1; m >>= 1) s += __shfl_xor(s, m, 64);
    if (lane == 0) esq[j] = s;
}

// embed -> fragment-major bf16 hi/lo for mfma_f32_16x16x32_bf16 B operand.
// Block b = ct*8 + s (ct: 16-col tile 0..63, s: 32-k step 0..7). Lane l holds
// col = ct*16 + (l&15), k = s*32 + (l>>4)*8 + i  (i=0..7), stored contiguous.
__global__ void efrag_kernel(const float* __restrict__ embed,
                             unsigned short* __restrict__ ehi,
                             unsigned short* __restrict__ elo) {
    const int b = blockIdx.x;          // 0..511
    const int l = threadIdx.x;         // 0..63
    const int ct = b >> 3, s = b & 7;
    const int col = ct * 16 + (l & 15);
    const int kb  = s * 32 + (l >> 4) * 8;
    const float* src = embed + (size_t)col * DIM + kb;
    float4 v0 = *reinterpret_cast<const float4*>(src);
    float4 v1 = *reinterpret_cast<const float4*>(src + 4);
    float vv[8] = {v0.x, v0.y, v0.z, v0.w, v1.x, v1.y, v1.z, v1.w};
    unsigned short hh[8], ll[8];
#pragma unroll
    for (int i = 0; i < 8; ++i) {
        unsigned short h = f32_to_bf16_rne(vv[i]);
        hh[i] = h;
        ll[i] = f32_to_bf16_rne(vv[i] - bf16_to_f32(h));
    }
    size_t base = ((size_t)b * 64 + l) * 8;
#pragma unroll
    for (int i = 0; i < 8; ++i) { ehi[base + i] = hh[i]; elo[base + i] = ll[i]; }
}

// ---- MFMA fast pass + exact-refine (block = 4 waves, 128 rows) ----
__global__ __launch_bounds__(256, 2)
void vq_mfma_kernel(const float* __restrict__ x, const float* __restrict__ embed,
                    const unsigned short* __restrict__ ehi,
                    const unsigned short* __restrict__ elo,
                    const float* __restrict__ esq, float* __restrict__ out,
                    int N, int K) {
    __shared__ float  esq_lds[1024];
    __shared__ double rv1[256], rv2[256];
    __shared__ int    ri1[256], ri2[256];
    __shared__ float  xrow[DIM];
    __shared__ int    flr[BMB];
    __shared__ int    nflag;

    const int t = threadIdx.x;
    const int w = t >> 6;        // wave 0..3
    const int l = t & 63;        // lane
    const int ar = l & 15;       // A-row / B-col / C-col lane field
    const int ag = l >> 4;       // k-group / C-row-group lane field
    const int row0  = blockIdx.x * BMB;
    const int wrow0 = row0 + w * 32;

    if (t == 0) nflag = 0;
    for (int i = t; i < 1024; i += 256) esq_lds[i] = esq[i];

    // A fragments (resident): 2 row-tiles x 8 k-steps, hi+lo
    short8 ahi[2][8], alo[2][8];
#pragma unroll
    for (int rt = 0; rt < 2; ++rt)
#pragma unroll
        for (int s = 0; s < 8; ++s) {
            const float* src = x + (size_t)(wrow0 + rt * 16 + ar) * DIM + s * 32 + ag * 8;
            float4 v0 = *reinterpret_cast<const float4*>(src);
            float4 v1 = *reinterpret_cast<const float4*>(src + 4);
            float vv[8] = {v0.x, v0.y, v0.z, v0.w, v1.x, v1.y, v1.z, v1.w};
#pragma unroll
            for (int i = 0; i < 8; ++i) {
                unsigned short h = f32_to_bf16_rne(vv[i]);
                ahi[rt][s][i] = (short)h;
                alo[rt][s][i] = (short)f32_to_bf16_rne(vv[i] - bf16_to_f32(h));
            }
        }
    __syncthreads();   // esq_lds ready; nflag init ordered

    float minv[8], min2v[8]; int mini[8];
#pragma unroll
    for (int i = 0; i < 8; ++i) { minv[i] = INFINITY; min2v[i] = INFINITY; mini[i] = 0; }

    for (int jc = 0; jc < 16; ++jc) {          // 16 chunks of 64 cols
        f32x4 acc[2][4];
#pragma unroll
        for (int rt = 0; rt < 2; ++rt)
#pragma unroll
            for (int ct = 0; ct < 4; ++ct) acc[rt][ct] = (f32x4)0.0f;

#pragma unroll
        for (int s = 0; s < 8; ++s) {
            short8 bhi[4], blo[4];
#pragma unroll
            for (int ct = 0; ct < 4; ++ct) {
                size_t base = (((size_t)(jc * 4 + ct) * 8 + s) * 64 + l) * 8;
                bhi[ct] = *reinterpret_cast<const short8*>(ehi + base);
                blo[ct] = *reinterpret_cast<const short8*>(elo + base);
            }
#pragma unroll
            for (int rt = 0; rt < 2; ++rt)
#pragma unroll
                for (int ct = 0; ct < 4; ++ct) {
                    acc[rt][ct] = __builtin_amdgcn_mfma_f32_16x16x32_bf16(
                        ahi[rt][s], bhi[ct], acc[rt][ct], 0, 0, 0);
                    acc[rt][ct] = __builtin_amdgcn_mfma_f32_16x16x32_bf16(
                        ahi[rt][s], blo[ct], acc[rt][ct], 0, 0, 0);
                    acc[rt][ct] = __builtin_amdgcn_mfma_f32_16x16x32_bf16(
                        alo[rt][s], bhi[ct], acc[rt][ct], 0, 0, 0);
                }
        }
        // epilogue: scores + per-lane top-2 (cols ascending -> first-index ties)
#pragma unroll
        for (int rt = 0; rt < 2; ++rt)
#pragma unroll
            for (int ct = 0; ct < 4; ++ct) {
                int col = jc * 64 + ct * 16 + ar;
                float eq = esq_lds[col];
#pragma unroll
                for (int r = 0; r < 4; ++r) {
                    float sc = fmaf(-2.0f, acc[rt][ct][r], eq);
                    int ii = rt * 4 + r;
                    if (sc < minv[ii]) { min2v[ii] = minv[ii]; minv[ii] = sc; mini[ii] = col; }
                    else if (sc < min2v[ii]) { min2v[ii] = sc; }
                }
            }
    }

    // cross-lane top-2 merge within each 16-lane group (masks 1,2,4,8)
#pragma unroll
    for (int ii = 0; ii < 8; ++ii) {
        float v1 = minv[ii]; int i1 = mini[ii]; float v2 = min2v[ii];
#pragma unroll
        for (int m = 1; m < 16; m <<= 1) {
            float ov1 = __shfl_xor(v1, m, 64);
            int   oi1 = __shfl_xor(i1, m, 64);
            float ov2 = __shfl_xor(v2, m, 64);
            float nv2 = fminf(fmaxf(v1, ov1), fminf(v2, ov2));
            if (ov1 < v1 || (ov1 == v1 && oi1 < i1)) { v1 = ov1; i1 = oi1; }
            v2 = nv2;
        }
        minv[ii] = v1; mini[ii] = i1; min2v[ii] = v2;
    }

    // outputs: [quantize | indices(as float) | residual]
    const size_t IOFF = (size_t)N * DIM;
    const size_t ROFF = IOFF + (size_t)N;
#pragma unroll
    for (int ii = 0; ii < 8; ++ii) {
        const int rt = ii >> 2, r = ii & 3;
        const int row = wrow0 + rt * 16 + ag * 4 + r;
        const int idx = mini[ii];
        if (ar == 0) {
            out[IOFF + row] = (float)idx;
            if (min2v[ii] - minv[ii] < MARGIN) {
                int p = atomicAdd(&nflag, 1);      // LDS atomic; p < BMB
                flr[p] = row - row0;
            }
        }
#pragma unroll
        for (int q = 0; q < 4; ++q) {
            int d0 = ar * 16 + q * 4;
            float4 e  = *reinterpret_cast<const float4*>(embed + (size_t)idx * DIM + d0);
            float4 xv = *reinterpret_cast<const float4*>(x + (size_t)row * DIM + d0);
            *reinterpret_cast<float4*>(out + (size_t)row * DIM + d0) = e;
            float4 rr = make_float4(e.x - xv.x, e.y - xv.y, e.z - xv.z, e.w - xv.w);
            *reinterpret_cast<float4*>(out + ROFF + (size_t)row * DIM + d0) = rr;
        }
    }

    // ---- exact (fp64) top-2 refinement + tie policy (R6-verified, unchanged) ----
    __syncthreads();
    const int nf = nflag;
    for (int f = 0; f < nf; ++f) {
        const int row = row0 + flr[f];
        if (t < 64) {
            float4 v = *reinterpret_cast<const float4*>(x + (size_t)row * DIM + t * 4);
            xrow[t * 4 + 0] = v.x; xrow[t * 4 + 1] = v.y;
            xrow[t * 4 + 2] = v.z; xrow[t * 4 + 3] = v.w;
        }
        __syncthreads();

        double v1 = DBL_MAX, v2 = DBL_MAX; int i1 = 0x7fffffff, i2 = 0x7fffffff;
#pragma unroll
        for (int jj = 0; jj < 4; ++jj) {
            const int j = t * 4 + jj;
            const float* e = embed + (size_t)j * DIM;
            double xe = 0.0, ee = 0.0;
            for (int kg = 0; kg < DIM / 4; ++kg) {
                float4 ev = *reinterpret_cast<const float4*>(e + kg * 4);
                double e0 = ev.x, e1 = ev.y, e2 = ev.z, e3 = ev.w;
                xe += e0 * (double)xrow[kg * 4 + 0] + e1 * (double)xrow[kg * 4 + 1]
                    + e2 * (double)xrow[kg * 4 + 2] + e3 * (double)xrow[kg * 4 + 3];
                ee += e0 * e0 + e1 * e1 + e2 * e2 + e3 * e3;
            }
            double d = ee - 2.0 * xe;            // shift-invariant score
            if (d < v1 || (d == v1 && j < i1)) { v2 = v1; i2 = i1; v1 = d; i1 = j; }
            else if (d < v2 || (d == v2 && j < i2)) { v2 = d; i2 = j; }
        }
        rv1[t] = v1; ri1[t] = i1; rv2[t] = v2; ri2[t] = i2;
        __syncthreads();
        for (int s = 128; s > 0; s >>= 1) {
            if (t < s) {
                double a1 = rv1[t],     a2 = rv2[t];     int k1 = ri1[t],     k2 = ri2[t];
                double b1 = rv1[t + s], b2 = rv2[t + s]; int j1 = ri1[t + s], j2 = ri2[t + s];
                double w1, w2; int m1, m2;
                bool bfirst = (b1 < a1) || (b1 == a1 && j1 < k1);
                if (bfirst) {
                    w1 = b1; m1 = j1;
                    if (a1 < b2 || (a1 == b2 && k1 < j2)) { w2 = a1; m2 = k1; }
                    else                                   { w2 = b2; m2 = j2; }
                } else {
                    w1 = a1; m1 = k1;
                    if (b1 < a2 || (b1 == a2 && j1 < k2)) { w2 = b1; m2 = j1; }
                    else                                   { w2 = a2; m2 = k2; }
                }
                rv1[t] = w1; ri1[t] = m1; rv2[t] = w2; ri2[t] = m2;
            }
            __syncthreads();
        }
        int idx = ri1[0];
        {
            const double gap = rv2[0] - rv1[0];
#if PREFER_LOWER
            if (gap < EPS_TIE && ri2[0] < ri1[0]) idx = ri2[0];
#else
            if (gap < EPS_TIE && ri2[0] > ri1[0]) idx = ri2[0];
#endif
        }
        if (t == 0) out[IOFF + row] = (float)idx;
        if (t < 64) {
            int d0 = t * 4;
            float4 e  = *reinterpret_cast<const float4*>(embed + (size_t)idx * DIM + d0);
            float4 xv = *reinterpret_cast<const float4*>(x + (size_t)row * DIM + d0);
            *reinterpret_cast<float4*>(out + (size_t)row * DIM + d0) = e;
            float4 rr = make_float4(e.x - xv.x, e.y - xv.y, e.z - xv.z, e.w - xv.w);
            *reinterpret_cast<float4*>(out + ROFF + (size_t)row * DIM + d0) = rr;
        }
        __syncthreads();
    }
}

// ================= fallback: R6-verified VALU path (used if ws too small) ====
#define BM 64
#define BN 64
#define DK 64
__global__ __launch_bounds__(256, 4)
void vq_argmin_kernel(const float* __restrict__ x, const float* __restrict__ embed,
                      const float* __restrict__ esq, float* __restrict__ out,
                      int N, int K) {
    __shared__ float xs[DK][BM];
    __shared__ float es[DK][BN];
    __shared__ double rv1[256], rv2[256];
    __shared__ int    ri1[256], ri2[256];
    __shared__ float  xrow[DIM];
    __shared__ int    flr[BM];
    __shared__ int    nflag;

    const int t = threadIdx.x;
    const int tx = t & 15, ty = t >> 4;
    const int row0 = blockIdx.x * BM;
    if (t == 0) nflag = 0;

    float minv[4], min2v[4]; int mini[4];
#pragma unroll
    for (int r = 0; r < 4; ++r) { minv[r] = INFINITY; min2v[r] = INFINITY; mini[r] = 0; }

    for (int jc = 0; jc < K / BN; ++jc) {
        float acc[4][4];
#pragma unroll
        for (int r = 0; r < 4; ++r)
#pragma unroll
            for (int c = 0; c < 4; ++c) acc[r][c] = 0.0f;
        for (int dc = 0; dc < DIM / DK; ++dc) {
            __syncthreads();
#pragma unroll
            for (int it = 0; it < 4; ++it) {
                int idx = t + 256 * it, r = idx & 63, kg = idx >> 6;
                float4 v = *reinterpret_cast<const float4*>(
                    x + (size_t)(row0 + r) * DIM + dc * DK + kg * 4);
                xs[kg*4+0][r] = v.x; xs[kg*4+1][r] = v.y; xs[kg*4+2][r] = v.z; xs[kg*4+3][r] = v.w;
            }
#pragma unroll
            for (int it = 0; it < 4; ++it) {
                int idx = t + 256 * it, c = idx & 63, kg = idx >> 6;
                float4 v = *reinterpret_cast<const float4*>(
                    embed + (size_t)(jc * BN + c) * DIM + dc * DK + kg * 4);
                es[kg*4+0][c] = v.x; es[kg*4+1][c] = v.y; es[kg*4+2][c] = v.z; es[kg*4+3][c] = v.w;
            }
            __syncthreads();
#pragma unroll
            for (int k = 0; k < DK; ++k) {
                float4 a = *reinterpret_cast<const float4*>(&xs[k][ty * 4]);
                float4 b = *reinterpret_cast<const float4*>(&es[k][tx * 4]);
                float arr[4] = {a.x, a.y, a.z, a.w}, bc[4] = {b.x, b.y, b.z, b.w};
#pragma unroll
                for (int r = 0; r < 4; ++r)
#pragma unroll
                    for (int c = 0; c < 4; ++c) acc[r][c] = fmaf(arr[r], bc[c], acc[r][c]);
            }
        }
        float4 eq = *reinterpret_cast<const float4*>(esq + jc * BN + tx * 4);
        float eqa[4] = {eq.x, eq.y, eq.z, eq.w};
#pragma unroll
        for (int c = 0; c < 4; ++c) {
            int j = jc * BN + tx * 4 + c;
#pragma unroll
            for (int r = 0; r < 4; ++r) {
                float s = fmaf(-2.0f, acc[r][c], eqa[c]);
                if (s < minv[r]) { min2v[r] = minv[r]; minv[r] = s; mini[r] = j; }
                else if (s < min2v[r]) { min2v[r] = s; }
            }
        }
    }
#pragma unroll
    for (int r = 0; r < 4; ++r) {
        float v1 = minv[r]; int i1 = mini[r]; float v2 = min2v[r];
#pragma unroll
        for (int m = 1; m < 16; m <<= 1) {
            float ov1 = __shfl_xor(v1, m, 64); int oi1 = __shfl_xor(i1, m, 64);
            float ov2 = __shfl_xor(v2, m, 64);
            float nv2 = fminf(fmaxf(v1, ov1), fminf(v2, ov2));
            if (ov1 < v1 || (ov1 == v1 && oi1 < i1)) { v1 = ov1; i1 = oi1; }
            v2 = nv2;
        }
        minv[r] = v1; mini[r] = i1; min2v[r] = v2;
    }
    const size_t IOFF = (size_t)N * DIM, ROFF = IOFF + (size_t)N;
#pragma unroll
    for (int r = 0; r < 4; ++r) {
        int row = row0 + ty * 4 + r, idx = mini[r];
        if (tx == 0) {
            out[IOFF + row] = (float)idx;
            if (min2v[r] - minv[r] < MARGIN) { int p = atomicAdd(&nflag, 1); flr[p] = ty * 4 + r; }
        }
#pragma unroll
        for (int g = 0; g < 4; ++g) {
            int d0 = tx * 16 + g * 4;
            float4 e  = *reinterpret_cast<const float4*>(embed + (size_t)idx * DIM + d0);
            float4 xv = *reinterpret_cast<const float4*>(x + (size_t)row * DIM + d0);
            *reinterpret_cast<float4*>(out + (size_t)row * DIM + d0) = e;
            float4 rr = make_float4(e.x - xv.x, e.y - xv.y, e.z - xv.z, e.w - xv.w);
            *reinterpret_cast<float4*>(out + ROFF + (size_t)row * DIM + d0) = rr;
        }
    }
    __syncthreads();
    const int nf = nflag;
    for (int f = 0; f < nf; ++f) {
        const int row = row0 + flr[f];
        if (t < 64) {
            float4 v = *reinterpret_cast<const float4*>(x + (size_t)row * DIM + t * 4);
            xrow[t*4+0] = v.x; xrow[t*4+1] = v.y; xrow[t*4+2] = v.z; xrow[t*4+3] = v.w;
        }
        __syncthreads();
        double v1 = DBL_MAX, v2 = DBL_MAX; int i1 = 0x7fffffff, i2 = 0x7fffffff;
#pragma unroll
        for (int jj = 0; jj < 4; ++jj) {
            const int j = t * 4 + jj;
            const float* e = embed + (size_t)j * DIM;
            double xe = 0.0, ee = 0.0;
            for (int kg = 0; kg < DIM / 4; ++kg) {
                float4 ev = *reinterpret_cast<const float4*>(e + kg * 4);
                double e0 = ev.x, e1 = ev.y, e2 = ev.z, e3 = ev.w;
                xe += e0*(double)xrow[kg*4+0] + e1*(double)xrow[kg*4+1]
                    + e2*(double)xrow[kg*4+2] + e3*(double)xrow[kg*4+3];
                ee += e0*e0 + e1*e1 + e2*e2 + e3*e3;
            }
            double d = ee - 2.0 * xe;
            if (d < v1 || (d == v1 && j < i1)) { v2 = v1; i2 = i1; v1 = d; i1 = j; }
            else if (d < v2 || (d == v2 && j < i2)) { v2 = d; i2 = j; }
        }
        rv1[t] = v1; ri1[t] = i1; rv2[t] = v2; ri2[t] = i2;
        __syncthreads();
        for (int s = 128; s > 0; s >>= 1) {
            if (t < s) {
                double a1 = rv1[t], a2 = rv2[t]; int k1 = ri1[t], k2 = ri2[t];
                double b1 = rv1[t+s], b2 = rv2[t+s]; int j1 = ri1[t+s], j2 = ri2[t+s];
                double w1, w2; int m1, m2;
                bool bfirst = (b1 < a1) || (b1 == a1 && j1 < k1);
                if (bfirst) { w1 = b1; m1 = j1;
                    if (a1 < b2 || (a1 == b2 && k1 < j2)) { w2 = a1; m2 = k1; } else { w2 = b2; m2 = j2; }
                } else { w1 = a1; m1 = k1;
                    if (b1 < a2 || (b1 == a2 && j1 < k2)) { w2 = b1; m2 = j1; } else { w2 = a2; m2 = k2; }
                }
                rv1[t] = w1; ri1[t] = m1; rv2[t] = w2; ri2[t] = m2;
            }
            __syncthreads();
        }
        int idx = ri1[0];
        const double gap = rv2[0] - rv1[0];
#if PREFER_LOWER
        if (gap < EPS_TIE && ri2[0] < ri1[0]) idx = ri2[0];
#else
        if (gap < EPS_TIE && ri2[0] > ri1[0]) idx = ri2[0];
#endif
        if (t == 0) out[IOFF + row] = (float)idx;
        if (t < 64) {
            int d0 = t * 4;
            float4 e  = *reinterpret_cast<const float4*>(embed + (size_t)idx * DIM + d0);
            float4 xv = *reinterpret_cast<const float4*>(x + (size_t)row * DIM + d0);
            *reinterpret_cast<float4*>(out + (size_t)row * DIM + d0) = e;
            float4 rr = make_float4(e.x - xv.x, e.y - xv.y, e.z - xv.z, e.w - xv.w);
            *reinterpret_cast<float4*>(out + ROFF + (size_t)row * DIM + d0) = rr;
        }
        __syncthreads();
    }
}

extern "C" void kernel_launch(void* const* d_in, const int* in_sizes, int n_in,
                              void* d_out, int out_size, void* d_ws, size_t ws_size,
                              hipStream_t stream) {
    const float* x     = (const float*)d_in[0];
    const float* embed = (const float*)d_in[1];
    float* out = (float*)d_out;
    const int N = in_sizes[0] / DIM;   // 65536
    const int K = in_sizes[1] / DIM;   // 1024

    // ws layout (MFMA path): [0,4KB) esq | [4KB, +512KB) ehi | [+512KB, +512KB) elo
    float* esq = (float*)d_ws;
    unsigned short* ehi = (unsigned short*)((char*)d_ws + 4096);
    unsigned short* elo = (unsigned short*)((char*)d_ws + 4096 + 524288);
    const size_t need = 4096 + 2 * 524288;

    esq_kernel<<<K, 64, 0, stream>>>(embed, esq);
    if (ws_size >= need) {
        efrag_kernel<<<(K / 16) * 8, 64, 0, stream>>>(embed, ehi, elo);
        vq_mfma_kernel<<<N / BMB, 256, 0, stream>>>(x, embed, ehi, elo, esq, out, N, K);
    } else {
        vq_argmin_kernel<<<N / BM, 256, 0, stream>>>(x, embed, esq, out, N, K);
    }
}

// Round 8
// 431.735 us; speedup vs baseline: 1.7721x; 1.0117x over previous
//
#include <hip/hip_runtime.h>
#include <math.h>
#include <float.h>

#define DIM 256
#define MARGIN 0.125f
// Tie policy (verified PASS in R6/R7 — do not change):
#define EPS_TIE 1e-4
#define PREFER_LOWER 1

#define BMB 128   // rows per block (MFMA path): 4 waves x 32 rows

typedef __attribute__((ext_vector_type(8))) short short8;   // 8 bf16 = 4 VGPR
typedef __attribute__((ext_vector_type(4))) float f32x4;    // MFMA acc

__device__ __forceinline__ unsigned short f32_to_bf16_rne(float f) {
    unsigned int u = __float_as_uint(f);
    u += 0x7fffu + ((u >> 16) & 1u);
    return (unsigned short)(u >> 16);
}
__device__ __forceinline__ float bf16_to_f32(unsigned short h) {
    return __uint_as_float((unsigned int)h << 16);
}

// |e_j|^2 (fast pass only needs approx); one wave per codebook row
__global__ void esq_kernel(const float* __restrict__ embed, float* __restrict__ esq) {
    const int j = blockIdx.x;
    const int lane = threadIdx.x;  // 64
    float4 v = *reinterpret_cast<const float4*>(embed + (size_t)j * DIM + lane * 4);
    float s = v.x * v.x + v.y * v.y + v.z * v.z + v.w * v.w;
#pragma unroll
    for (int m = 32; m >= 1; m >>= 1) s += __shfl_xor(s, m, 64);
    if (lane == 0) esq[j] = s;
}

// embed -> fragment-major bf16 hi/lo for mfma_f32_16x16x32_bf16 B operand.
// Block b = ct*8 + s (ct: 16-col tile 0..63, s: 32-k step 0..7). Lane l holds
// col = ct*16 + (l&15), k = s*32 + (l>>4)*8 + i  (i=0..7), stored contiguous.
__global__ void efrag_kernel(const float* __restrict__ embed,
                             unsigned short* __restrict__ ehi,
                             unsigned short* __restrict__ elo) {
    const int b = blockIdx.x;          // 0..511
    const int l = threadIdx.x;         // 0..63
    const int ct = b >> 3, s = b & 7;
    const int col = ct * 16 + (l & 15);
    const int kb  = s * 32 + (l >> 4) * 8;
    const float* src = embed + (size_t)col * DIM + kb;
    float4 v0 = *reinterpret_cast<const float4*>(src);
    float4 v1 = *reinterpret_cast<const float4*>(src + 4);
    float vv[8] = {v0.x, v0.y, v0.z, v0.w, v1.x, v1.y, v1.z, v1.w};
    unsigned short hh[8], ll[8];
#pragma unroll
    for (int i = 0; i < 8; ++i) {
        unsigned short h = f32_to_bf16_rne(vv[i]);
        hh[i] = h;
        ll[i] = f32_to_bf16_rne(vv[i] - bf16_to_f32(h));
    }
    size_t base = ((size_t)b * 64 + l) * 8;
#pragma unroll
    for (int i = 0; i < 8; ++i) { ehi[base + i] = hh[i]; elo[base + i] = ll[i]; }
}

// ---- MFMA fast pass + exact-refine (block = 4 waves, 128 rows) ----
// B-fragment loads are register double-buffered: loads for step s+1 issue
// before the MFMAs of step s, so they stay in flight (counted vmcnt) under
// the 24-MFMA cluster instead of stalling serially (R7: MfmaUtil 9%).
__global__ __launch_bounds__(256, 2)
void vq_mfma_kernel(const float* __restrict__ x, const float* __restrict__ embed,
                    const unsigned short* __restrict__ ehi,
                    const unsigned short* __restrict__ elo,
                    const float* __restrict__ esq, float* __restrict__ out,
                    int N, int K) {
    __shared__ float  esq_lds[1024];
    __shared__ double rv1[256], rv2[256];
    __shared__ int    ri1[256], ri2[256];
    __shared__ float  xrow[DIM];
    __shared__ int    flr[BMB];
    __shared__ int    nflag;

    const int t = threadIdx.x;
    const int w = t >> 6;        // wave 0..3
    const int l = t & 63;        // lane
    const int ar = l & 15;       // A-row / B-col / C-col lane field
    const int ag = l >> 4;       // k-group / C-row-group lane field
    const int row0  = blockIdx.x * BMB;
    const int wrow0 = row0 + w * 32;

    if (t == 0) nflag = 0;
    for (int i = t; i < 1024; i += 256) esq_lds[i] = esq[i];

    // A fragments (resident): 2 row-tiles x 8 k-steps, hi+lo (128 VGPR)
    short8 ahi[2][8], alo[2][8];
#pragma unroll
    for (int rt = 0; rt < 2; ++rt)
#pragma unroll
        for (int s = 0; s < 8; ++s) {
            const float* src = x + (size_t)(wrow0 + rt * 16 + ar) * DIM + s * 32 + ag * 8;
            float4 v0 = *reinterpret_cast<const float4*>(src);
            float4 v1 = *reinterpret_cast<const float4*>(src + 4);
            float vv[8] = {v0.x, v0.y, v0.z, v0.w, v1.x, v1.y, v1.z, v1.w};
#pragma unroll
            for (int i = 0; i < 8; ++i) {
                unsigned short h = f32_to_bf16_rne(vv[i]);
                ahi[rt][s][i] = (short)h;
                alo[rt][s][i] = (short)f32_to_bf16_rne(vv[i] - bf16_to_f32(h));
            }
        }
    __syncthreads();   // esq_lds ready; nflag init ordered

    float minv[8], min2v[8]; int mini[8];
#pragma unroll
    for (int i = 0; i < 8; ++i) { minv[i] = INFINITY; min2v[i] = INFINITY; mini[i] = 0; }

    // B double buffers (parity-static: even s -> consume b0, prefetch b1)
    short8 b0h[4], b0l[4], b1h[4], b1l[4];
#pragma unroll
    for (int ct = 0; ct < 4; ++ct) {       // prologue: (jc=0, s=0) into b0
        size_t base = (((size_t)ct * 8 + 0) * 64 + l) * 8;
        b0h[ct] = *reinterpret_cast<const short8*>(ehi + base);
        b0l[ct] = *reinterpret_cast<const short8*>(elo + base);
    }

    f32x4 acc[2][4];
#pragma unroll
    for (int rt = 0; rt < 2; ++rt)
#pragma unroll
        for (int ct = 0; ct < 4; ++ct) acc[rt][ct] = (f32x4)0.0f;

    for (int jc = 0; jc < 16; ++jc) {          // runtime loop (addresses only)
#pragma unroll
        for (int s = 0; s < 8; ++s) {          // unrolled: s, parity compile-time
            // prefetch step s+1 (wraps to next jc; jc=15,s=7 wraps to jc0 harmlessly)
            const int ns  = (s + 1) & 7;
            const int njc = (jc + ((s + 1) >> 3)) & 15;
#pragma unroll
            for (int ct = 0; ct < 4; ++ct) {
                size_t nb = (((size_t)(njc * 4 + ct) * 8 + ns) * 64 + l) * 8;
                if ((s & 1) == 0) {
                    b1h[ct] = *reinterpret_cast<const short8*>(ehi + nb);
                    b1l[ct] = *reinterpret_cast<const short8*>(elo + nb);
                } else {
                    b0h[ct] = *reinterpret_cast<const short8*>(ehi + nb);
                    b0l[ct] = *reinterpret_cast<const short8*>(elo + nb);
                }
            }
            // consume current buffer (static parity)
#pragma unroll
            for (int rt = 0; rt < 2; ++rt)
#pragma unroll
                for (int ct = 0; ct < 4; ++ct) {
                    if ((s & 1) == 0) {
                        acc[rt][ct] = __builtin_amdgcn_mfma_f32_16x16x32_bf16(
                            ahi[rt][s], b0h[ct], acc[rt][ct], 0, 0, 0);
                        acc[rt][ct] = __builtin_amdgcn_mfma_f32_16x16x32_bf16(
                            ahi[rt][s], b0l[ct], acc[rt][ct], 0, 0, 0);
                        acc[rt][ct] = __builtin_amdgcn_mfma_f32_16x16x32_bf16(
                            alo[rt][s], b0h[ct], acc[rt][ct], 0, 0, 0);
                    } else {
                        acc[rt][ct] = __builtin_amdgcn_mfma_f32_16x16x32_bf16(
                            ahi[rt][s], b1h[ct], acc[rt][ct], 0, 0, 0);
                        acc[rt][ct] = __builtin_amdgcn_mfma_f32_16x16x32_bf16(
                            ahi[rt][s], b1l[ct], acc[rt][ct], 0, 0, 0);
                        acc[rt][ct] = __builtin_amdgcn_mfma_f32_16x16x32_bf16(
                            alo[rt][s], b1h[ct], acc[rt][ct], 0, 0, 0);
                    }
                }
        }
        // epilogue: scores + per-lane top-2 (cols ascending -> first-index ties)
#pragma unroll
        for (int rt = 0; rt < 2; ++rt)
#pragma unroll
            for (int ct = 0; ct < 4; ++ct) {
                int col = jc * 64 + ct * 16 + ar;
                float eq = esq_lds[col];
#pragma unroll
                for (int r = 0; r < 4; ++r) {
                    float sc = fmaf(-2.0f, acc[rt][ct][r], eq);
                    int ii = rt * 4 + r;
                    if (sc < minv[ii]) { min2v[ii] = minv[ii]; minv[ii] = sc; mini[ii] = col; }
                    else if (sc < min2v[ii]) { min2v[ii] = sc; }
                }
                acc[rt][ct] = (f32x4)0.0f;
            }
    }

    // cross-lane top-2 merge within each 16-lane group (masks 1,2,4,8)
#pragma unroll
    for (int ii = 0; ii < 8; ++ii) {
        float v1 = minv[ii]; int i1 = mini[ii]; float v2 = min2v[ii];
#pragma unroll
        for (int m = 1; m < 16; m <<= 1) {
            float ov1 = __shfl_xor(v1, m, 64);
            int   oi1 = __shfl_xor(i1, m, 64);
            float ov2 = __shfl_xor(v2, m, 64);
            float nv2 = fminf(fmaxf(v1, ov1), fminf(v2, ov2));
            if (ov1 < v1 || (ov1 == v1 && oi1 < i1)) { v1 = ov1; i1 = oi1; }
            v2 = nv2;
        }
        minv[ii] = v1; mini[ii] = i1; min2v[ii] = v2;
    }

    // outputs: [quantize | indices(as float) | residual]
    const size_t IOFF = (size_t)N * DIM;
    const size_t ROFF = IOFF + (size_t)N;
#pragma unroll
    for (int ii = 0; ii < 8; ++ii) {
        const int rt = ii >> 2, r = ii & 3;
        const int row = wrow0 + rt * 16 + ag * 4 + r;
        const int idx = mini[ii];
        if (ar == 0) {
            out[IOFF + row] = (float)idx;
            if (min2v[ii] - minv[ii] < MARGIN) {
                int p = atomicAdd(&nflag, 1);      // LDS atomic; p < BMB
                flr[p] = row - row0;
            }
        }
#pragma unroll
        for (int q = 0; q < 4; ++q) {
            int d0 = ar * 16 + q * 4;
            float4 e  = *reinterpret_cast<const float4*>(embed + (size_t)idx * DIM + d0);
            float4 xv = *reinterpret_cast<const float4*>(x + (size_t)row * DIM + d0);
            *reinterpret_cast<float4*>(out + (size_t)row * DIM + d0) = e;
            float4 rr = make_float4(e.x - xv.x, e.y - xv.y, e.z - xv.z, e.w - xv.w);
            *reinterpret_cast<float4*>(out + ROFF + (size_t)row * DIM + d0) = rr;
        }
    }

    // ---- exact (fp64) top-2 refinement + tie policy (R6-verified, unchanged) ----
    __syncthreads();
    const int nf = nflag;
    for (int f = 0; f < nf; ++f) {
        const int row = row0 + flr[f];
        if (t < 64) {
            float4 v = *reinterpret_cast<const float4*>(x + (size_t)row * DIM + t * 4);
            xrow[t * 4 + 0] = v.x; xrow[t * 4 + 1] = v.y;
            xrow[t * 4 + 2] = v.z; xrow[t * 4 + 3] = v.w;
        }
        __syncthreads();

        double v1 = DBL_MAX, v2 = DBL_MAX; int i1 = 0x7fffffff, i2 = 0x7fffffff;
#pragma unroll
        for (int jj = 0; jj < 4; ++jj) {
            const int j = t * 4 + jj;
            const float* e = embed + (size_t)j * DIM;
            double xe = 0.0, ee = 0.0;
            for (int kg = 0; kg < DIM / 4; ++kg) {
                float4 ev = *reinterpret_cast<const float4*>(e + kg * 4);
                double e0 = ev.x, e1 = ev.y, e2 = ev.z, e3 = ev.w;
                xe += e0 * (double)xrow[kg * 4 + 0] + e1 * (double)xrow[kg * 4 + 1]
                    + e2 * (double)xrow[kg * 4 + 2] + e3 * (double)xrow[kg * 4 + 3];
                ee += e0 * e0 + e1 * e1 + e2 * e2 + e3 * e3;
            }
            double d = ee - 2.0 * xe;            // shift-invariant score
            if (d < v1 || (d == v1 && j < i1)) { v2 = v1; i2 = i1; v1 = d; i1 = j; }
            else if (d < v2 || (d == v2 && j < i2)) { v2 = d; i2 = j; }
        }
        rv1[t] = v1; ri1[t] = i1; rv2[t] = v2; ri2[t] = i2;
        __syncthreads();
        for (int s = 128; s > 0; s >>= 1) {
            if (t < s) {
                double a1 = rv1[t],     a2 = rv2[t];     int k1 = ri1[t],     k2 = ri2[t];
                double b1 = rv1[t + s], b2 = rv2[t + s]; int j1 = ri1[t + s], j2 = ri2[t + s];
                double w1, w2; int m1, m2;
                bool bfirst = (b1 < a1) || (b1 == a1 && j1 < k1);
                if (bfirst) {
                    w1 = b1; m1 = j1;
                    if (a1 < b2 || (a1 == b2 && k1 < j2)) { w2 = a1; m2 = k1; }
                    else                                   { w2 = b2; m2 = j2; }
                } else {
                    w1 = a1; m1 = k1;
                    if (b1 < a2 || (b1 == a2 && j1 < k2)) { w2 = b1; m2 = j1; }
                    else                                   { w2 = a2; m2 = k2; }
                }
                rv1[t] = w1; ri1[t] = m1; rv2[t] = w2; ri2[t] = m2;
            }
            __syncthreads();
        }
        int idx = ri1[0];
        {
            const double gap = rv2[0] - rv1[0];
#if PREFER_LOWER
            if (gap < EPS_TIE && ri2[0] < ri1[0]) idx = ri2[0];
#else
            if (gap < EPS_TIE && ri2[0] > ri1[0]) idx = ri2[0];
#endif
        }
        if (t == 0) out[IOFF + row] = (float)idx;
        if (t < 64) {
            int d0 = t * 4;
            float4 e  = *reinterpret_cast<const float4*>(embed + (size_t)idx * DIM + d0);
            float4 xv = *reinterpret_cast<const float4*>(x + (size_t)row * DIM + d0);
            *reinterpret_cast<float4*>(out + (size_t)row * DIM + d0) = e;
            float4 rr = make_float4(e.x - xv.x, e.y - xv.y, e.z - xv.z, e.w - xv.w);
            *reinterpret_cast<float4*>(out + ROFF + (size_t)row * DIM + d0) = rr;
        }
        __syncthreads();
    }
}

// ================= fallback: R6-verified VALU path (used if ws too small) ====
#define BM 64
#define BN 64
#define DK 64
__global__ __launch_bounds__(256, 4)
void vq_argmin_kernel(const float* __restrict__ x, const float* __restrict__ embed,
                      const float* __restrict__ esq, float* __restrict__ out,
                      int N, int K) {
    __shared__ float xs[DK][BM];
    __shared__ float es[DK][BN];
    __shared__ double rv1[256], rv2[256];
    __shared__ int    ri1[256], ri2[256];
    __shared__ float  xrow[DIM];
    __shared__ int    flr[BM];
    __shared__ int    nflag;

    const int t = threadIdx.x;
    const int tx = t & 15, ty = t >> 4;
    const int row0 = blockIdx.x * BM;
    if (t == 0) nflag = 0;

    float minv[4], min2v[4]; int mini[4];
#pragma unroll
    for (int r = 0; r < 4; ++r) { minv[r] = INFINITY; min2v[r] = INFINITY; mini[r] = 0; }

    for (int jc = 0; jc < K / BN; ++jc) {
        float acc[4][4];
#pragma unroll
        for (int r = 0; r < 4; ++r)
#pragma unroll
            for (int c = 0; c < 4; ++c) acc[r][c] = 0.0f;
        for (int dc = 0; dc < DIM / DK; ++dc) {
            __syncthreads();
#pragma unroll
            for (int it = 0; it < 4; ++it) {
                int idx = t + 256 * it, r = idx & 63, kg = idx >> 6;
                float4 v = *reinterpret_cast<const float4*>(
                    x + (size_t)(row0 + r) * DIM + dc * DK + kg * 4);
                xs[kg*4+0][r] = v.x; xs[kg*4+1][r] = v.y; xs[kg*4+2][r] = v.z; xs[kg*4+3][r] = v.w;
            }
#pragma unroll
            for (int it = 0; it < 4; ++it) {
                int idx = t + 256 * it, c = idx & 63, kg = idx >> 6;
                float4 v = *reinterpret_cast<const float4*>(
                    embed + (size_t)(jc * BN + c) * DIM + dc * DK + kg * 4);
                es[kg*4+0][c] = v.x; es[kg*4+1][c] = v.y; es[kg*4+2][c] = v.z; es[kg*4+3][c] = v.w;
            }
            __syncthreads();
#pragma unroll
            for (int k = 0; k < DK; ++k) {
                float4 a = *reinterpret_cast<const float4*>(&xs[k][ty * 4]);
                float4 b = *reinterpret_cast<const float4*>(&es[k][tx * 4]);
                float arr[4] = {a.x, a.y, a.z, a.w}, bc[4] = {b.x, b.y, b.z, b.w};
#pragma unroll
                for (int r = 0; r < 4; ++r)
#pragma unroll
                    for (int c = 0; c < 4; ++c) acc[r][c] = fmaf(arr[r], bc[c], acc[r][c]);
            }
        }
        float4 eq = *reinterpret_cast<const float4*>(esq + jc * BN + tx * 4);
        float eqa[4] = {eq.x, eq.y, eq.z, eq.w};
#pragma unroll
        for (int c = 0; c < 4; ++c) {
            int j = jc * BN + tx * 4 + c;
#pragma unroll
            for (int r = 0; r < 4; ++r) {
                float s = fmaf(-2.0f, acc[r][c], eqa[c]);
                if (s < minv[r]) { min2v[r] = minv[r]; minv[r] = s; mini[r] = j; }
                else if (s < min2v[r]) { min2v[r] = s; }
            }
        }
    }
#pragma unroll
    for (int r = 0; r < 4; ++r) {
        float v1 = minv[r]; int i1 = mini[r]; float v2 = min2v[r];
#pragma unroll
        for (int m = 1; m < 16; m <<= 1) {
            float ov1 = __shfl_xor(v1, m, 64); int oi1 = __shfl_xor(i1, m, 64);
            float ov2 = __shfl_xor(v2, m, 64);
            float nv2 = fminf(fmaxf(v1, ov1), fminf(v2, ov2));
            if (ov1 < v1 || (ov1 == v1 && oi1 < i1)) { v1 = ov1; i1 = oi1; }
            v2 = nv2;
        }
        minv[r] = v1; mini[r] = i1; min2v[r] = v2;
    }
    const size_t IOFF = (size_t)N * DIM, ROFF = IOFF + (size_t)N;
#pragma unroll
    for (int r = 0; r < 4; ++r) {
        int row = row0 + ty * 4 + r, idx = mini[r];
        if (tx == 0) {
            out[IOFF + row] = (float)idx;
            if (min2v[r] - minv[r] < MARGIN) { int p = atomicAdd(&nflag, 1); flr[p] = ty * 4 + r; }
        }
#pragma unroll
        for (int g = 0; g < 4; ++g) {
            int d0 = tx * 16 + g * 4;
            float4 e  = *reinterpret_cast<const float4*>(embed + (size_t)idx * DIM + d0);
            float4 xv = *reinterpret_cast<const float4*>(x + (size_t)row * DIM + d0);
            *reinterpret_cast<float4*>(out + (size_t)row * DIM + d0) = e;
            float4 rr = make_float4(e.x - xv.x, e.y - xv.y, e.z - xv.z, e.w - xv.w);
            *reinterpret_cast<float4*>(out + ROFF + (size_t)row * DIM + d0) = rr;
        }
    }
    __syncthreads();
    const int nf = nflag;
    for (int f = 0; f < nf; ++f) {
        const int row = row0 + flr[f];
        if (t < 64) {
            float4 v = *reinterpret_cast<const float4*>(x + (size_t)row * DIM + t * 4);
            xrow[t*4+0] = v.x; xrow[t*4+1] = v.y; xrow[t*4+2] = v.z; xrow[t*4+3] = v.w;
        }
        __syncthreads();
        double v1 = DBL_MAX, v2 = DBL_MAX; int i1 = 0x7fffffff, i2 = 0x7fffffff;
#pragma unroll
        for (int jj = 0; jj < 4; ++jj) {
            const int j = t * 4 + jj;
            const float* e = embed + (size_t)j * DIM;
            double xe = 0.0, ee = 0.0;
            for (int kg = 0; kg < DIM / 4; ++kg) {
                float4 ev = *reinterpret_cast<const float4*>(e + kg * 4);
                double e0 = ev.x, e1 = ev.y, e2 = ev.z, e3 = ev.w;
                xe += e0*(double)xrow[kg*4+0] + e1*(double)xrow[kg*4+1]
                    + e2*(double)xrow[kg*4+2] + e3*(double)xrow[kg*4+3];
                ee += e0*e0 + e1*e1 + e2*e2 + e3*e3;
            }
            double d = ee - 2.0 * xe;
            if (d < v1 || (d == v1 && j < i1)) { v2 = v1; i2 = i1; v1 = d; i1 = j; }
            else if (d < v2 || (d == v2 && j < i2)) { v2 = d; i2 = j; }
        }
        rv1[t] = v1; ri1[t] = i1; rv2[t] = v2; ri2[t] = i2;
        __syncthreads();
        for (int s = 128; s > 0; s >>= 1) {
            if (t < s) {
                double a1 = rv1[t], a2 = rv2[t]; int k1 = ri1[t], k2 = ri2[t];
                double b1 = rv1[t+s], b2 = rv2[t+s]; int j1 = ri1[t+s], j2 = ri2[t+s];
                double w1, w2; int m1, m2;
                bool bfirst = (b1 < a1) || (b1 == a1 && j1 < k1);
                if (bfirst) { w1 = b1; m1 = j1;
                    if (a1 < b2 || (a1 == b2 && k1 < j2)) { w2 = a1; m2 = k1; } else { w2 = b2; m2 = j2; }
                } else { w1 = a1; m1 = k1;
                    if (b1 < a2 || (b1 == a2 && j1 < k2)) { w2 = b1; m2 = j1; } else { w2 = a2; m2 = k2; }
                }
                rv1[t] = w1; ri1[t] = m1; rv2[t] = w2; ri2[t] = m2;
            }
            __syncthreads();
        }
        int idx = ri1[0];
        const double gap = rv2[0] - rv1[0];
#if PREFER_LOWER
        if (gap < EPS_TIE && ri2[0] < ri1[0]) idx = ri2[0];
#else
        if (gap < EPS_TIE && ri2[0] > ri1[0]) idx = ri2[0];
#endif
        if (t == 0) out[IOFF + row] = (float)idx;
        if (t < 64) {
            int d0 = t * 4;
            float4 e  = *reinterpret_cast<const float4*>(embed + (size_t)idx * DIM + d0);
            float4 xv = *reinterpret_cast<const float4*>(x + (size_t)row * DIM + d0);
            *reinterpret_cast<float4*>(out + (size_t)row * DIM + d0) = e;
            float4 rr = make_float4(e.x - xv.x, e.y - xv.y, e.z - xv.z, e.w - xv.w);
            *reinterpret_cast<float4*>(out + ROFF + (size_t)row * DIM + d0) = rr;
        }
        __syncthreads();
    }
}

extern "C" void kernel_launch(void* const* d_in, const int* in_sizes, int n_in,
                              void* d_out, int out_size, void* d_ws, size_t ws_size,
                              hipStream_t stream) {
    const float* x     = (const float*)d_in[0];
    const float* embed = (const float*)d_in[1];
    float* out = (float*)d_out;
    const int N = in_sizes[0] / DIM;   // 65536
    const int K = in_sizes[1] / DIM;   // 1024

    // ws layout (MFMA path): [0,4KB) esq | [4KB, +512KB) ehi | [+512KB, +512KB) elo
    float* esq = (float*)d_ws;
    unsigned short* ehi = (unsigned short*)((char*)d_ws + 4096);
    unsigned short* elo = (unsigned short*)((char*)d_ws + 4096 + 524288);
    const size_t need = 4096 + 2 * 524288;

    esq_kernel<<<K, 64, 0, stream>>>(embed, esq);
    if (ws_size >= need) {
        efrag_kernel<<<(K / 16) * 8, 64, 0, stream>>>(embed, ehi, elo);
        vq_mfma_kernel<<<N / BMB, 256, 0, stream>>>(x, embed, ehi, elo, esq, out, N, K);
    } else {
        vq_argmin_kernel<<<N / BM, 256, 0, stream>>>(x, embed, esq, out, N, K);
    }
}